// Round 1
// baseline (14790.216 us; speedup 1.0000x reference)
//
#include <hip/hip_runtime.h>
#include <stdint.h>

#define T_LEN 128
#define BATCH 128
#define DHID 512
#define H 256
#define NTAGS 60
#define START_TAG 58
#define STOP_TAG 59
#define NEGV -10000.0f

typedef __attribute__((ext_vector_type(8))) short bf16x8;
typedef __attribute__((ext_vector_type(4))) float floatx4;
typedef unsigned short u16;

__device__ __forceinline__ u16 f2bf(float f) {
  union { float f; uint32_t u; } c; c.f = f;
  uint32_t u = c.u;
  u += 0x7FFFu + ((u >> 16) & 1u);
  return (u16)(u >> 16);
}
__device__ __forceinline__ float bf2f(u16 h) {
  union { uint32_t u; float f; } c; c.u = ((uint32_t)h) << 16;
  return c.f;
}
__device__ __forceinline__ float sigmf(float x) { return 1.0f / (1.0f + __expf(-x)); }
__device__ __forceinline__ float tanhfast(float x) {
  x = fminf(fmaxf(x, -15.0f), 15.0f);
  float e = __expf(2.0f * x);
  return (e - 1.0f) / (e + 1.0f);
}

// ---------------------------------------------------------------------------
// Pack fp32 weights -> bf16 workspace copies.
// whh_bf: [7][2][1024][256]  (layer0 from w_hh1, layers1..6 from w_hh)
// wih_bf: [6][2][1024][512]
// fcw_bf: [64][512] (rows 60..63 zero)
// ---------------------------------------------------------------------------
__global__ void pack_kernel(const float* __restrict__ whh1, const float* __restrict__ whh,
                            const float* __restrict__ wih, const float* __restrict__ fcw,
                            u16* __restrict__ whh_bf, u16* __restrict__ wih_bf,
                            u16* __restrict__ fcw_bf) {
  const int n_whh1 = 2 * 1024 * 256;
  const int n_whh  = 6 * 2 * 1024 * 256;
  const int n_wih  = 6 * 2 * 1024 * 512;
  const int n_fcw  = 64 * 512;
  const int total = n_whh1 + n_whh + n_wih + n_fcw;
  for (int i = blockIdx.x * blockDim.x + threadIdx.x; i < total; i += gridDim.x * blockDim.x) {
    if (i < n_whh1) {
      whh_bf[i] = f2bf(whh1[i]);
    } else if (i < n_whh1 + n_whh) {
      whh_bf[i] = f2bf(whh[i - n_whh1]);
    } else if (i < n_whh1 + n_whh + n_wih) {
      int j = i - n_whh1 - n_whh;
      wih_bf[j] = f2bf(wih[j]);
    } else {
      int j = i - n_whh1 - n_whh - n_wih;
      int row = j >> 9;
      fcw_bf[j] = (row < NTAGS) ? f2bf(fcw[j]) : (u16)0;
    }
  }
}

// ---------------------------------------------------------------------------
// Layer-1 xw: Din=3. xw[row][dir*1024+n] = sum_d x[row][d]*w_ih1[dir][n][d] + b1
// row = t*128+b. One thread per output. Grid: 131072 x 256.
// ---------------------------------------------------------------------------
__global__ void xw1_kernel(const float* __restrict__ sent, const float* __restrict__ wih1,
                           const float* __restrict__ b1, u16* __restrict__ xw) {
  int idx = blockIdx.x * blockDim.x + threadIdx.x;
  int row = idx >> 11, col = idx & 2047;
  const float* x = sent + row * 3;
  const float* w = wih1 + col * 3;
  float a = b1[col] + x[0] * w[0] + x[1] * w[1] + x[2] * w[2];
  xw[idx] = f2bf(a);
}

// ---------------------------------------------------------------------------
// xw GEMM for layers 2..7: A = relu(cur) [+ relu(prev)], [16384 x 512]
// W: [2048 rows (dir*1024+n)] x [512] (bf16, row-major, = B^T so frag loads are
// contiguous along K). bias: [2048] fp32. Out: xw [16384][2048] bf16.
// Grid: (8 N-chunks of 256, 256 M-tiles of 64). Block 256 (4 waves, wave=16 rows).
// ---------------------------------------------------------------------------
__launch_bounds__(256, 4)
__global__ void gemm_xw_kernel(const u16* __restrict__ cur, const u16* __restrict__ prev,
                               const u16* __restrict__ W, const float* __restrict__ bias,
                               u16* __restrict__ xw) {
  __shared__ __align__(16) u16 As[64][72];
  const int nbase = blockIdx.x * 256;
  const int m0 = blockIdx.y * 64;
  const int tid = threadIdx.x;
  const int wv = tid >> 6, ln = tid & 63;
  const int c16 = ln & 15, q = ln >> 4;

  floatx4 acc[16];
#pragma unroll
  for (int i = 0; i < 16; ++i) { acc[i][0] = 0.f; acc[i][1] = 0.f; acc[i][2] = 0.f; acc[i][3] = 0.f; }

  for (int kc = 0; kc < 8; ++kc) {
    // stage A[64][64] (relu + optional residual)
    {
      int u = tid * 2;
#pragma unroll
      for (int z = 0; z < 2; ++z, ++u) {
        int r = u >> 3, cu = (u & 7) * 8;
        int gaddr = (m0 + r) * DHID + kc * 64 + cu;
        bf16x8 a8 = *(const bf16x8*)(cur + gaddr);
        u16* ap = (u16*)&a8;
        if (prev) {
          bf16x8 p8 = *(const bf16x8*)(prev + gaddr);
          u16* pp = (u16*)&p8;
#pragma unroll
          for (int e = 0; e < 8; ++e) {
            float va = (ap[e] & 0x8000) ? 0.f : bf2f(ap[e]);
            float vp = (pp[e] & 0x8000) ? 0.f : bf2f(pp[e]);
            ap[e] = f2bf(va + vp);
          }
        } else {
#pragma unroll
          for (int e = 0; e < 8; ++e) if (ap[e] & 0x8000) ap[e] = 0;
        }
        *(bf16x8*)(&As[r][cu]) = a8;
      }
    }
    __syncthreads();
#pragma unroll
    for (int kt = 0; kt < 2; ++kt) {
      bf16x8 a = *(const bf16x8*)(&As[wv * 16 + c16][kt * 32 + q * 8]);
      int kg = kc * 64 + kt * 32 + q * 8;
#pragma unroll
      for (int half = 0; half < 2; ++half) {
        bf16x8 bfr[8];
#pragma unroll
        for (int nn = 0; nn < 8; ++nn) {
          int n = nbase + (half * 8 + nn) * 16 + c16;
          bfr[nn] = *(const bf16x8*)(W + n * DHID + kg);
        }
#pragma unroll
        for (int nn = 0; nn < 8; ++nn)
          acc[half * 8 + nn] =
              __builtin_amdgcn_mfma_f32_16x16x32_bf16(a, bfr[nn], acc[half * 8 + nn], 0, 0, 0);
      }
    }
    __syncthreads();
  }
#pragma unroll
  for (int nt = 0; nt < 16; ++nt) {
    int col = nbase + nt * 16 + c16;
    float bv = bias[col];
#pragma unroll
    for (int r = 0; r < 4; ++r) {
      int row = m0 + wv * 16 + q * 4 + r;
      xw[row * 2048 + col] = f2bf(acc[nt][r] + bv);
    }
  }
}

// ---------------------------------------------------------------------------
// Persistent LSTM scan for one layer. Grid: (4 batch-chunks of 32, 2 dirs).
// Block 512 (8 waves). Wave w owns h-columns [32w, 32w+32) => all 4 gates of
// those columns live in the same lanes (zero gate exchange). h in LDS
// (double-buffered), c in registers. W_hh B-frags streamed from L2 each step.
// whh: [2][1024][256] bf16. xw: [16384][2048] bf16. h0/c0: [2][128][256] fp32.
// obuf: [16384][512] bf16 (col = dir*256 + j).
// ---------------------------------------------------------------------------
__launch_bounds__(512, 2)
__global__ void scan_kernel(const u16* __restrict__ whh, const u16* __restrict__ xw,
                            const float* __restrict__ h0, const float* __restrict__ c0,
                            u16* __restrict__ obuf) {
  __shared__ __align__(16) u16 hbuf[2][32][264];
  const int b0 = blockIdx.x * 32;
  const int dir = blockIdx.y;
  const int tid = threadIdx.x;
  const int wv = tid >> 6, ln = tid & 63;
  const int c16 = ln & 15, q = ln >> 4;

  // init h (bf16) into hbuf[0]
#pragma unroll
  for (int e = 0; e < 16; ++e) {
    int idx = e * 512 + tid;
    int r = idx >> 8, cc = idx & 255;
    hbuf[0][r][cc] = f2bf(h0[(dir * BATCH + b0 + r) * H + cc]);
  }
  // init c (fp32) into registers; lane mapping matches the D-fragment layout
  float creg[2][2][4];
#pragma unroll
  for (int mt = 0; mt < 2; ++mt)
#pragma unroll
    for (int st = 0; st < 2; ++st)
#pragma unroll
      for (int r = 0; r < 4; ++r) {
        int b = b0 + mt * 16 + q * 4 + r;
        int j = wv * 32 + st * 16 + c16;
        creg[mt][st][r] = c0[(dir * BATCH + b) * H + j];
      }
  __syncthreads();

  const u16* wbase = whh + dir * 1024 * H;
  for (int s = 0; s < T_LEN; ++s) {
    const int t = dir ? (T_LEN - 1 - s) : s;
    const int cb = s & 1, nb = cb ^ 1;

    // A fragments from LDS h
    bf16x8 afrag[2][8];
#pragma unroll
    for (int mt = 0; mt < 2; ++mt)
#pragma unroll
      for (int kt = 0; kt < 8; ++kt)
        afrag[mt][kt] = *(const bf16x8*)(&hbuf[cb][mt * 16 + c16][kt * 32 + q * 8]);

    // acc init = xw_t (bias + input GEMM already folded in)
    floatx4 acc[4][2][2];
    const int rowb = t * BATCH + b0;
#pragma unroll
    for (int g = 0; g < 4; ++g)
#pragma unroll
      for (int st = 0; st < 2; ++st) {
        int col = dir * 1024 + g * H + (wv * 2 + st) * 16 + c16;
#pragma unroll
        for (int mt = 0; mt < 2; ++mt)
#pragma unroll
          for (int r = 0; r < 4; ++r)
            acc[g][st][mt][r] = bf2f(xw[(rowb + mt * 16 + q * 4 + r) * 2048 + col]);
      }

    // recurrent GEMM: stream B-frags of W_hh from L2
#pragma unroll
    for (int g = 0; g < 4; ++g)
#pragma unroll
      for (int st = 0; st < 2; ++st) {
        int n = g * H + (wv * 2 + st) * 16 + c16;
        const u16* wrow = wbase + n * H;
        bf16x8 bfr[8];
#pragma unroll
        for (int kt = 0; kt < 8; ++kt) bfr[kt] = *(const bf16x8*)(wrow + kt * 32 + q * 8);
#pragma unroll
        for (int kt = 0; kt < 8; ++kt)
#pragma unroll
          for (int mt = 0; mt < 2; ++mt)
            acc[g][st][mt] =
                __builtin_amdgcn_mfma_f32_16x16x32_bf16(afrag[mt][kt], bfr[kt], acc[g][st][mt], 0, 0, 0);
      }

    // gates, c/h update, write h' (LDS next buffer + global obuf)
#pragma unroll
    for (int mt = 0; mt < 2; ++mt)
#pragma unroll
      for (int st = 0; st < 2; ++st)
#pragma unroll
        for (int r = 0; r < 4; ++r) {
          float iv = acc[0][st][mt][r];
          float fv = acc[1][st][mt][r];
          float gv = acc[2][st][mt][r];
          float ov = acc[3][st][mt][r];
          float ig = sigmf(iv), fg = sigmf(fv), og = sigmf(ov);
          float gg = tanhfast(gv);
          float cn = fg * creg[mt][st][r] + ig * gg;
          creg[mt][st][r] = cn;
          float hv = og * tanhfast(cn);
          u16 hb = f2bf(hv);
          int rloc = mt * 16 + q * 4 + r;
          int j = wv * 32 + st * 16 + c16;
          hbuf[nb][rloc][j] = hb;
          obuf[(t * BATCH + b0 + rloc) * DHID + dir * H + j] = hb;
        }
    __syncthreads();
  }
}

// ---------------------------------------------------------------------------
// FC: feats[16384][64] fp32 = out7[16384][512] @ fcw^T + fc_b  (cols >=60 unused)
// Grid: 256 blocks of 256 (4 waves, wave = 16 rows).
// ---------------------------------------------------------------------------
__launch_bounds__(256, 4)
__global__ void fc_kernel(const u16* __restrict__ A, const u16* __restrict__ W,
                          const float* __restrict__ fb, float* __restrict__ feats) {
  const int tid = threadIdx.x, wv = tid >> 6, ln = tid & 63;
  const int c16 = ln & 15, q = ln >> 4;
  const int m0 = blockIdx.x * 64 + wv * 16;
  floatx4 acc[4];
#pragma unroll
  for (int i = 0; i < 4; ++i) { acc[i][0] = 0.f; acc[i][1] = 0.f; acc[i][2] = 0.f; acc[i][3] = 0.f; }
#pragma unroll
  for (int kt = 0; kt < 16; ++kt) {
    bf16x8 a = *(const bf16x8*)(A + (m0 + c16) * DHID + kt * 32 + q * 8);
#pragma unroll
    for (int nt = 0; nt < 4; ++nt) {
      bf16x8 b = *(const bf16x8*)(W + (nt * 16 + c16) * DHID + kt * 32 + q * 8);
      acc[nt] = __builtin_amdgcn_mfma_f32_16x16x32_bf16(a, b, acc[nt], 0, 0, 0);
    }
  }
#pragma unroll
  for (int nt = 0; nt < 4; ++nt) {
    int n = nt * 16 + c16;
    if (n < NTAGS) {
      float bv = fb[n];
#pragma unroll
      for (int r = 0; r < 4; ++r)
        feats[(m0 + q * 4 + r) * 64 + n] = acc[nt][r] + bv;
    }
  }
}

// ---------------------------------------------------------------------------
// CRF: one wave (64 threads) per batch item. lane = next-tag. Two-pass LSE.
// Gold path score fused. out[b] = log_z - gold.
// ---------------------------------------------------------------------------
__launch_bounds__(64, 1)
__global__ void crf_kernel(const float* __restrict__ feats, const float* __restrict__ trans,
                           const int* __restrict__ tags, float* __restrict__ out) {
  __shared__ float Tl[60][65];
  __shared__ float abuf[2][64];
  const int b = blockIdx.x;
  const int ln = threadIdx.x;
  for (int i = ln; i < 3600; i += 64) Tl[i / 60][i % 60] = trans[i];
  __syncthreads();

  // gold score
  float gsc = 0.f;
  for (int t = ln; t < T_LEN; t += 64) {
    int tg = tags[t * BATCH + b];
    int pv = (t == 0) ? START_TAG : tags[(t - 1) * BATCH + b];
    gsc += Tl[tg][pv] + feats[(t * BATCH + b) * 64 + tg];
  }
#pragma unroll
  for (int off = 32; off > 0; off >>= 1) gsc += __shfl_down(gsc, off);
  if (ln == 0) gsc += Tl[STOP_TAG][tags[(T_LEN - 1) * BATCH + b]];

  // alpha recurrence
  abuf[0][ln] = (ln == START_TAG) ? 0.f : NEGV;
  __syncthreads();
  const float* Trow = Tl[ln < NTAGS ? ln : 0];
  const int myk = (ln < NTAGS) ? ln : 0;
  for (int t = 0; t < T_LEN; ++t) {
    const int cb = t & 1, nb2 = cb ^ 1;
    float m = -1e30f;
    for (int p = 0; p < NTAGS; ++p) m = fmaxf(m, abuf[cb][p] + Trow[p]);
    float ssum = 0.f;
    for (int p = 0; p < NTAGS; ++p) ssum += __expf(abuf[cb][p] + Trow[p] - m);
    float nv = m + __logf(ssum) + feats[(t * BATCH + b) * 64 + myk];
    abuf[nb2][ln] = (ln < NTAGS) ? nv : NEGV;
    __syncthreads();
  }

  // log_z = LSE_n(alpha[n] + T[STOP][n])
  float v = (ln < NTAGS) ? (abuf[T_LEN & 1][ln] + Tl[STOP_TAG][ln]) : -1e30f;
  float mm = v;
#pragma unroll
  for (int off = 32; off > 0; off >>= 1) mm = fmaxf(mm, __shfl_down(mm, off));
  mm = __shfl(mm, 0);
  float es = __expf(v - mm);
#pragma unroll
  for (int off = 32; off > 0; off >>= 1) es += __shfl_down(es, off);
  if (ln == 0) out[b] = mm + __logf(es) - gsc;
}

// ---------------------------------------------------------------------------
extern "C" void kernel_launch(void* const* d_in, const int* in_sizes, int n_in,
                              void* d_out, int out_size, void* d_ws, size_t ws_size,
                              hipStream_t stream) {
  (void)in_sizes; (void)n_in; (void)out_size; (void)ws_size;
  const float* sent  = (const float*)d_in[0];
  const int*   tags  = (const int*)d_in[1];
  const float* wih1  = (const float*)d_in[2];
  const float* whh1  = (const float*)d_in[3];
  const float* b1    = (const float*)d_in[4];
  const float* wih   = (const float*)d_in[5];
  const float* whh   = (const float*)d_in[6];
  const float* bias  = (const float*)d_in[7];
  const float* fcw   = (const float*)d_in[8];
  const float* fcb   = (const float*)d_in[9];
  const float* h0    = (const float*)d_in[10];
  const float* c0    = (const float*)d_in[11];
  const float* trans = (const float*)d_in[12];
  float* out = (float*)d_out;

  char* ws = (char*)d_ws;
  size_t off = 0;
  auto alloc = [&](size_t bytes) -> void* {
    void* p = ws + off;
    off = (off + bytes + 255) & ~(size_t)255;
    return p;
  };
  u16* whh_bf = (u16*)alloc((size_t)7 * 2 * 1024 * 256 * 2);
  u16* wih_bf = (u16*)alloc((size_t)6 * 2 * 1024 * 512 * 2);
  u16* fcw_bf = (u16*)alloc((size_t)64 * 512 * 2);
  u16* xw     = (u16*)alloc((size_t)16384 * 2048 * 2);
  u16* ob[3];
  for (int i = 0; i < 3; ++i) ob[i] = (u16*)alloc((size_t)16384 * 512 * 2);
  float* feats = (float*)alloc((size_t)16384 * 64 * 4);

  hipLaunchKernelGGL(pack_kernel, dim3(4096), dim3(256), 0, stream,
                     whh1, whh, wih, fcw, whh_bf, wih_bf, fcw_bf);
  hipLaunchKernelGGL(xw1_kernel, dim3(131072), dim3(256), 0, stream, sent, wih1, b1, xw);
  hipLaunchKernelGGL(scan_kernel, dim3(4, 2), dim3(512), 0, stream,
                     whh_bf, xw, h0, c0, ob[0]);
  for (int L = 1; L < 7; ++L) {
    const u16* curb = ob[(L - 1) % 3];
    const u16* prevb = (L >= 2) ? ob[(L - 2) % 3] : nullptr;
    hipLaunchKernelGGL(gemm_xw_kernel, dim3(8, 256), dim3(256), 0, stream,
                       curb, prevb, wih_bf + (size_t)(L - 1) * 2 * 1024 * 512,
                       bias + (size_t)(L - 1) * 2048, xw);
    hipLaunchKernelGGL(scan_kernel, dim3(4, 2), dim3(512), 0, stream,
                       whh_bf + (size_t)L * 2 * 1024 * 256, xw,
                       h0 + (size_t)L * 2 * 128 * 256, c0 + (size_t)L * 2 * 128 * 256,
                       ob[L % 3]);
  }
  hipLaunchKernelGGL(fc_kernel, dim3(256), dim3(256), 0, stream, ob[0], fcw_bf, fcb, feats);
  hipLaunchKernelGGL(crf_kernel, dim3(128), dim3(64), 0, stream, feats, trans, tags, out);
}